// Round 8
// baseline (2535.358 us; speedup 1.0000x reference)
//
#include <hip/hip_runtime.h>

#define N_NODES 100000
#define N_GRAPHS 64
#define N_EDGES 600000
#define BN_EPS 1e-5f

// mega-kernel phase block counts (512 threads/block)
#define NB_HIST 1172   // ceil(600000/512)
#define NB_PRE  1563   // ceil(100000/64)
#define NB_SCAN 196    // ceil(100001/512)
#define NB_FILL 1172   // ceil(600000/512)
#define NB_TILE 1563   // ceil(100000/64), per layer

typedef unsigned short bf16_t;

__device__ __forceinline__ unsigned short f2bf(float f) {
    unsigned int u = __float_as_uint(f);
    u += 0x7FFF + ((u >> 16) & 1);
    return (unsigned short)(u >> 16);
}
__device__ __forceinline__ uint2 pack4(float a, float b, float c, float d) {
    uint2 p;
    p.x = (unsigned)f2bf(a) | ((unsigned)f2bf(b) << 16);
    p.y = (unsigned)f2bf(c) | ((unsigned)f2bf(d) << 16);
    return p;
}
// accumulate 8 bf16 (uint4) into acc[0..7]
__device__ __forceinline__ void bf8_acc(uint4 q, float* acc) {
    acc[0] += __uint_as_float(q.x << 16);
    acc[1] += __uint_as_float(q.x & 0xFFFF0000u);
    acc[2] += __uint_as_float(q.y << 16);
    acc[3] += __uint_as_float(q.y & 0xFFFF0000u);
    acc[4] += __uint_as_float(q.z << 16);
    acc[5] += __uint_as_float(q.z & 0xFFFF0000u);
    acc[6] += __uint_as_float(q.w << 16);
    acc[7] += __uint_as_float(q.w & 0xFFFF0000u);
}

// ---------------------------------------------------------------------------
// Phase-gating primitives (ticket pattern, deadlock-free: a block only ever
// waits on counters incremented by EARLIER-ticket blocks, which are already
// running or done). Release: stores -> sync -> per-thread fence -> sync ->
// one device-scope atomicAdd. Acquire: spin -> sync -> per-thread fence.
// ---------------------------------------------------------------------------
__device__ __forceinline__ void publish(int* c) {
    __syncthreads();
    __threadfence();
    __syncthreads();
    if (threadIdx.x == 0) atomicAdd(c, 1);
}
__device__ __forceinline__ void wait_count(int* c, int target) {
    if (threadIdx.x == 0) {
        while (atomicAdd(c, 0) < target) __builtin_amdgcn_s_sleep(8);
    }
    __syncthreads();
    __threadfence();
}

// ---------------------------------------------------------------------------
// Gather one 64-node tile into LDS (stride SS), bias+ReLU applied.
// R3-proven form: 512-thread single pass, 8 lanes/node, unroll-4 + tail.
// ---------------------------------------------------------------------------
template <int SS>
__device__ __forceinline__ void gather_tile_to_lds512(
    const bf16_t* __restrict__ y, const int* __restrict__ rowptr,
    const int* __restrict__ eids, const float* __restrict__ b1,
    float* sT, long base, int n_nodes, int tid) {
    const uint4* yv = (const uint4*)y;
    const int f = tid & 7;
    const int lr = tid >> 3;   // local row 0..63
    float4 b0 = ((const float4*)b1)[f * 2];
    float4 b1v = ((const float4*)b1)[f * 2 + 1];
    long node = base + lr;
    float* sp = &sT[lr * SS + f * 8];
    if (node < n_nodes) {
        float acc[8] = {};
        bf8_acc(yv[node * 8 + f], acc);
        int bgn = rowptr[node], end = rowptr[node + 1];
        int i = bgn;
        for (; i + 3 < end; i += 4) {
            int s0 = eids[i], s1 = eids[i + 1], s2 = eids[i + 2], s3 = eids[i + 3];
            uint4 q0 = yv[(long)s0 * 8 + f];
            uint4 q1 = yv[(long)s1 * 8 + f];
            uint4 q2 = yv[(long)s2 * 8 + f];
            uint4 q3 = yv[(long)s3 * 8 + f];
            bf8_acc(q0, acc); bf8_acc(q1, acc); bf8_acc(q2, acc); bf8_acc(q3, acc);
        }
        for (; i < end; ++i) bf8_acc(yv[(long)eids[i] * 8 + f], acc);
        float4 o0, o1;
        o0.x = fmaxf(acc[0] + b0.x, 0.0f);
        o0.y = fmaxf(acc[1] + b0.y, 0.0f);
        o0.z = fmaxf(acc[2] + b0.z, 0.0f);
        o0.w = fmaxf(acc[3] + b0.w, 0.0f);
        o1.x = fmaxf(acc[4] + b1v.x, 0.0f);
        o1.y = fmaxf(acc[5] + b1v.y, 0.0f);
        o1.z = fmaxf(acc[6] + b1v.z, 0.0f);
        o1.w = fmaxf(acc[7] + b1v.w, 0.0f);
        *(float4*)sp = o0;
        *(float4*)(sp + 4) = o1;
    } else {
        float4 z = {0.0f, 0.0f, 0.0f, 0.0f};
        *(float4*)sp = z;
        *(float4*)(sp + 4) = z;
    }
}

// ---------------------------------------------------------------------------
// Phase bodies (verbatim R3/R4 math; smem is the shared union pool)
// ---------------------------------------------------------------------------

// pre: y = x @ W1_0 (128 -> 64), bf16 out. 512 threads, 2 rows/thread.
__device__ void pre_phase(float* smem, int tile, const float* __restrict__ x,
                          const float* __restrict__ w1T, bf16_t* __restrict__ y,
                          int n_nodes, int tid) {
    float* w1s = smem;  // 64*128
    const long base = (long)tile * 64;

    const float4* gw1 = (const float4*)w1T;
    for (int i4 = tid; i4 < 16 * 128; i4 += 512) {
        int row = i4 >> 5, k4 = i4 & 31;
        *(float4*)&w1s[row * 128 + ((k4 ^ ((row >> 2) & 7)) << 2)] = gw1[i4];
    }
    __syncthreads();

    const int jg = tid & 15, ng = tid >> 4, xw = jg & 7;  // ng 0..31, 2 rows
    const float* wp = &w1s[(jg * 4) * 128];
    const float4* xv = (const float4*)x;
    long r[2];
    #pragma unroll
    for (int i = 0; i < 2; ++i) {
        long rr = base + ng * 2 + i;
        r[i] = (rr < n_nodes) ? rr : (n_nodes - 1);  // clamp: x has no padding
    }
    float acc[2][4] = {};
    #pragma unroll 4
    for (int k4 = 0; k4 < 32; ++k4) {
        const int ko = (k4 ^ xw) << 2;
        float4 w0 = *(const float4*)&wp[0 * 128 + ko];
        float4 w1v = *(const float4*)&wp[1 * 128 + ko];
        float4 w2v = *(const float4*)&wp[2 * 128 + ko];
        float4 w3v = *(const float4*)&wp[3 * 128 + ko];
        #pragma unroll
        for (int i = 0; i < 2; ++i) {
            float4 a = xv[r[i] * 32 + k4];
            acc[i][0] = fmaf(a.x, w0.x, fmaf(a.y, w0.y, fmaf(a.z, w0.z, fmaf(a.w, w0.w, acc[i][0]))));
            acc[i][1] = fmaf(a.x, w1v.x, fmaf(a.y, w1v.y, fmaf(a.z, w1v.z, fmaf(a.w, w1v.w, acc[i][1]))));
            acc[i][2] = fmaf(a.x, w2v.x, fmaf(a.y, w2v.y, fmaf(a.z, w2v.z, fmaf(a.w, w2v.w, acc[i][2]))));
            acc[i][3] = fmaf(a.x, w3v.x, fmaf(a.y, w3v.y, fmaf(a.z, w3v.z, fmaf(a.w, w3v.w, acc[i][3]))));
        }
    }
    #pragma unroll
    for (int i = 0; i < 2; ++i) {
        long n = base + ng * 2 + i;
        if (n < n_nodes) {
            *(uint2*)(y + n * 64 + jg * 4) = pack4(acc[i][0], acc[i][1], acc[i][2], acc[i][3]);
        }
    }
}

// mid: gather -> h = relu(t@W2s + bias2) -> ynext = h @ W1n (bf16 out)
__device__ void mid_phase(float* smem, int tile,
                          const bf16_t* __restrict__ y,
                          const int* __restrict__ rowptr, const int* __restrict__ eids,
                          const float* __restrict__ b1, const float* __restrict__ w2sT,
                          const float* __restrict__ bias2, const float* __restrict__ w1nT,
                          bf16_t* __restrict__ ynext, int n_nodes, int tid) {
    constexpr int SS = 68;
    float* sT = smem;            // 64*68
    float* wbuf = smem + 64 * SS; // 64*64
    const long base = (long)tile * 64;

    const float4* gw2 = (const float4*)w2sT;
    for (int i4 = tid; i4 < 16 * 64; i4 += 512) {
        int row = i4 >> 4, k4 = i4 & 15;
        *(float4*)&wbuf[row * 64 + ((k4 ^ ((row >> 2) & 7)) << 2)] = gw2[i4];
    }
    gather_tile_to_lds512<SS>(y, rowptr, eids, b1, sT, base, n_nodes, tid);
    __syncthreads();

    const int jg = tid & 15, ng = tid >> 4, xw = jg & 7;  // ng 0..31, 2 rows

    float h[2][4];
    {
        const float* wp = &wbuf[(jg * 4) * 64];
        float acc[2][4] = {};
        #pragma unroll 4
        for (int k4 = 0; k4 < 16; ++k4) {
            const int ko = (k4 ^ xw) << 2;
            float4 w0 = *(const float4*)&wp[0 * 64 + ko];
            float4 w1v = *(const float4*)&wp[1 * 64 + ko];
            float4 w2v = *(const float4*)&wp[2 * 64 + ko];
            float4 w3v = *(const float4*)&wp[3 * 64 + ko];
            #pragma unroll
            for (int i = 0; i < 2; ++i) {
                float4 a = *(const float4*)&sT[(ng * 2 + i) * SS + k4 * 4];
                acc[i][0] = fmaf(a.x, w0.x, fmaf(a.y, w0.y, fmaf(a.z, w0.z, fmaf(a.w, w0.w, acc[i][0]))));
                acc[i][1] = fmaf(a.x, w1v.x, fmaf(a.y, w1v.y, fmaf(a.z, w1v.z, fmaf(a.w, w1v.w, acc[i][1]))));
                acc[i][2] = fmaf(a.x, w2v.x, fmaf(a.y, w2v.y, fmaf(a.z, w2v.z, fmaf(a.w, w2v.w, acc[i][2]))));
                acc[i][3] = fmaf(a.x, w3v.x, fmaf(a.y, w3v.y, fmaf(a.z, w3v.z, fmaf(a.w, w3v.w, acc[i][3]))));
            }
        }
        float4 bv = *(const float4*)&bias2[jg * 4];
        #pragma unroll
        for (int i = 0; i < 2; ++i) {
            h[i][0] = fmaxf(acc[i][0] + bv.x, 0.0f);
            h[i][1] = fmaxf(acc[i][1] + bv.y, 0.0f);
            h[i][2] = fmaxf(acc[i][2] + bv.z, 0.0f);
            h[i][3] = fmaxf(acc[i][3] + bv.w, 0.0f);
        }
    }
    __syncthreads();

    #pragma unroll
    for (int i = 0; i < 2; ++i) {
        float4 hv = {h[i][0], h[i][1], h[i][2], h[i][3]};
        *(float4*)&sT[(ng * 2 + i) * SS + jg * 4] = hv;
    }
    const float4* gw1n = (const float4*)w1nT;
    for (int i4 = tid; i4 < 16 * 64; i4 += 512) {
        int row = i4 >> 4, k4 = i4 & 15;
        *(float4*)&wbuf[row * 64 + ((k4 ^ ((row >> 2) & 7)) << 2)] = gw1n[i4];
    }
    __syncthreads();

    {
        const float* ap = &sT[(ng * 2) * SS];
        const float* wp = &wbuf[(jg * 4) * 64];
        float acc[2][4] = {};
        #pragma unroll 4
        for (int k4 = 0; k4 < 16; ++k4) {
            const int ko = (k4 ^ xw) << 2;
            float4 w0 = *(const float4*)&wp[0 * 64 + ko];
            float4 w1v = *(const float4*)&wp[1 * 64 + ko];
            float4 w2v = *(const float4*)&wp[2 * 64 + ko];
            float4 w3v = *(const float4*)&wp[3 * 64 + ko];
            #pragma unroll
            for (int i = 0; i < 2; ++i) {
                float4 a = *(const float4*)&ap[i * SS + k4 * 4];
                acc[i][0] = fmaf(a.x, w0.x, fmaf(a.y, w0.y, fmaf(a.z, w0.z, fmaf(a.w, w0.w, acc[i][0]))));
                acc[i][1] = fmaf(a.x, w1v.x, fmaf(a.y, w1v.y, fmaf(a.z, w1v.z, fmaf(a.w, w1v.w, acc[i][1]))));
                acc[i][2] = fmaf(a.x, w2v.x, fmaf(a.y, w2v.y, fmaf(a.z, w2v.z, fmaf(a.w, w2v.w, acc[i][2]))));
                acc[i][3] = fmaf(a.x, w3v.x, fmaf(a.y, w3v.y, fmaf(a.z, w3v.z, fmaf(a.w, w3v.w, acc[i][3]))));
            }
        }
        #pragma unroll
        for (int i = 0; i < 2; ++i) {
            long n = base + ng * 2 + i;
            if (n < n_nodes) {
                *(uint2*)(ynext + n * 64 + jg * 4) = pack4(acc[i][0], acc[i][1], acc[i][2], acc[i][3]);
            }
        }
    }
}

// final: gather -> out96 = relu(t@W2s + bias2) -> per-graph mean-pool
__device__ void final_phase(float* smem, int tile,
                            const bf16_t* __restrict__ y,
                            const int* __restrict__ rowptr, const int* __restrict__ eids,
                            const float* __restrict__ b1, const float* __restrict__ w2sT,
                            const float* __restrict__ bias2, const int* __restrict__ batch,
                            const int* __restrict__ gstart, float* __restrict__ out,
                            int n_nodes, int tid) {
    constexpr int CPT = 6;
    constexpr int SS = 68;
    float* w2s = smem;             // 96*64, later reused as hbuf[64][96]
    float* tbuf = smem + 96 * 64;  // 64*68
    const long base = (long)tile * 64;

    const float4* gw2 = (const float4*)w2sT;
    for (int i4 = tid; i4 < 96 * 16; i4 += 512) {
        int row = i4 >> 4, k4 = i4 & 15;
        *(float4*)&w2s[row * 64 + ((k4 ^ ((row / CPT) & 7)) << 2)] = gw2[i4];
    }
    gather_tile_to_lds512<SS>(y, rowptr, eids, b1, tbuf, base, n_nodes, tid);
    __syncthreads();

    const int cg_ = tid & 15, ng = tid >> 4, xw = cg_ & 7;  // ng 0..31
    const float* wp = &w2s[(cg_ * CPT) * 64];
    float acc[2][CPT] = {};
    #pragma unroll 4
    for (int k4 = 0; k4 < 16; ++k4) {
        const int ko = (k4 ^ xw) << 2;
        float4 wv[CPT];
        #pragma unroll
        for (int c = 0; c < CPT; ++c) wv[c] = *(const float4*)&wp[c * 64 + ko];
        #pragma unroll
        for (int i = 0; i < 2; ++i) {
            float4 h = *(const float4*)&tbuf[(ng * 2 + i) * SS + k4 * 4];
            #pragma unroll
            for (int c = 0; c < CPT; ++c)
                acc[i][c] = fmaf(h.x, wv[c].x, fmaf(h.y, wv[c].y, fmaf(h.z, wv[c].z, fmaf(h.w, wv[c].w, acc[i][c]))));
        }
    }
    float bv[CPT];
    #pragma unroll
    for (int c = 0; c < CPT; ++c) bv[c] = bias2[cg_ * CPT + c];
    __syncthreads();  // all w2s weight reads done; buffer becomes hbuf
    #pragma unroll
    for (int i = 0; i < 2; ++i) {
        long n = base + ng * 2 + i;
        float* hp = &w2s[(ng * 2 + i) * 96 + cg_ * CPT];
        if (n < n_nodes) {
            #pragma unroll
            for (int c = 0; c < CPT; ++c) hp[c] = fmaxf(acc[i][c] + bv[c], 0.0f);
        } else {
            #pragma unroll
            for (int c = 0; c < CPT; ++c) hp[c] = 0.0f;
        }
    }
    __syncthreads();

    if (tid < 96) {
        int limit = (int)((n_nodes - base < 64) ? (n_nodes - base) : 64);
        int gcur = batch[base];
        float s = 0.0f;
        for (int r = 0; r < limit; ++r) {
            int g = batch[base + r];
            if (g != gcur) {
                float inv = 1.0f / fmaxf((float)(gstart[gcur + 1] - gstart[gcur]), 1.0f);
                atomicAdd(&out[gcur * 96 + tid], s * inv);
                s = 0.0f;
                gcur = g;
            }
            s += w2s[r * 96 + tid];
        }
        float inv = 1.0f / fmaxf((float)(gstart[gcur + 1] - gstart[gcur]), 1.0f);
        atomicAdd(&out[gcur * 96 + tid], s * inv);
    }
}

// ---------------------------------------------------------------------------
// Prep (blockIdx.y = layer); y==0 blocks also zero deg/cursor/d_out, init
// scan aggregates to -1 and phase counters to 0.
// ---------------------------------------------------------------------------
struct LayerPrep {
    const float *w1, *w2, *b2, *g, *bb, *m, *v;
    float *w1T, *w2sT, *bias2;
    int DIN, DOUT;
};
struct PrepAll { LayerPrep l[3]; };

__global__ void prep_all_kernel(PrepAll pa, int* __restrict__ deg,
                                int* __restrict__ cursor, float* __restrict__ out_zero,
                                int* __restrict__ agg, int* __restrict__ ctr) {
    LayerPrep P = pa.l[blockIdx.y];
    int i = blockIdx.x * blockDim.x + threadIdx.x;
    if (blockIdx.y == 0) {
        int stride = gridDim.x * blockDim.x;
        for (int k = i; k < N_NODES; k += stride) { deg[k] = 0; cursor[k] = 0; }
        for (int k = i; k < N_GRAPHS * 96; k += stride) out_zero[k] = 0.0f;
        if (i < 256) agg[i] = -1;
        if (i < 16) ctr[i] = 0;
    }
    if (i < 64 * P.DIN) {
        int j = i / P.DIN, k = i % P.DIN;
        P.w1T[i] = P.w1[k * 64 + j];
    }
    int i2 = i - 64 * P.DIN;
    if (i2 >= 0 && i2 < P.DOUT * 64) {
        int c = i2 / 64, j = i2 % 64;
        float s = P.g[c] * rsqrtf(P.v[c] + BN_EPS);
        P.w2sT[i2] = P.w2[j * P.DOUT + c] * s;
    }
    int i3 = i2 - P.DOUT * 64;
    if (i3 >= 0 && i3 < P.DOUT) {
        float s = P.g[i3] * rsqrtf(P.v[i3] + BN_EPS);
        P.bias2[i3] = (P.b2[i3] - P.m[i3]) * s + P.bb[i3];
    }
}

// ---------------------------------------------------------------------------
// MEGA kernel: all phases in one dispatch, ticket-gated.
// ticket ranges: [hist | pre | scan | fill | L0 | L1 | L2]
// ctr[0]=ticket ctr[1]=done_hist ctr[2]=done_fill+pre ctr[3]=done_scan
// ctr[4]=done_L0 ctr[5]=done_L1
// ---------------------------------------------------------------------------
struct MegaArgs {
    const int *src, *dst, *batch;
    const float* x;
    int *deg, *cursor, *rowptr, *eids, *gstart, *agg, *ctr;
    bf16_t *yA, *yB;
    const float *w1T0;
    const float *b1_0, *w2sT0, *bias2_0, *w1T1;
    const float *b1_1, *w2sT1, *bias2_1, *w1T2;
    const float *b1_2, *w2sT2, *bias2_2;
    float* out;
};

__global__ __launch_bounds__(512)
void mega_kernel(MegaArgs a) {
    __shared__ float smem[10496];   // 41984 B union pool (max: final phase)
    __shared__ int ticket_sh;
    __shared__ int offset_sh;
    const int tid = threadIdx.x;
    if (tid == 0) ticket_sh = atomicAdd(&a.ctr[0], 1);
    __syncthreads();
    const int t = ticket_sh;

    if (t < NB_HIST) {
        // ---------------- hist: deg histogram (deg pre-zeroed by prep) -----
        int e = t * 512 + tid;
        if (e < N_EDGES) atomicAdd(&a.deg[a.dst[e]], 1);
        publish(&a.ctr[1]);
    } else if (t < NB_HIST + NB_PRE) {
        // ---------------- pre: y = x @ W1_0 (no gate; overlaps scan/fill) --
        pre_phase(smem, t - NB_HIST, a.x, a.w1T0, a.yA, N_NODES, tid);
        publish(&a.ctr[2]);
    } else if (t < NB_HIST + NB_PRE + NB_SCAN) {
        // ---------------- scan: exclusive prefix over deg -> rowptr --------
        wait_count(&a.ctr[1], NB_HIST);
        const int sb = t - (NB_HIST + NB_PRE);
        int* s = (int*)smem;      // 512
        int* s2 = s + 512;        // 256
        const int i = sb * 512 + tid;
        int v = (i < N_NODES) ? a.deg[i] : 0;
        s[tid] = v;
        __syncthreads();
        for (int off = 1; off < 512; off <<= 1) {
            int tv = (tid >= off) ? s[tid - off] : 0;
            __syncthreads();
            s[tid] += tv;
            __syncthreads();
        }
        if (tid == 511) atomicExch(&a.agg[sb], s[511]);
        if (tid < sb) {
            int val;
            do { val = atomicAdd(&a.agg[tid], 0); } while (val == -1);
            s2[tid] = val;
        }
        __syncthreads();
        if (tid == 0) {
            int o = 0;
            for (int k = 0; k < sb; ++k) o += s2[k];
            offset_sh = o;
        }
        __syncthreads();
        const int off = offset_sh;
        if (i < N_NODES) a.rowptr[i] = off + s[tid] - v;
        else if (i == N_NODES) a.rowptr[N_NODES] = N_EDGES;
        publish(&a.ctr[3]);
    } else if (t < NB_HIST + NB_PRE + NB_SCAN + NB_FILL) {
        // ---------------- fill: CSR eids scatter + graph bounds ------------
        wait_count(&a.ctr[3], NB_SCAN);
        const int fb = t - (NB_HIST + NB_PRE + NB_SCAN);
        int e = fb * 512 + tid;
        if (e < N_EDGES) {
            int tn = a.dst[e];
            int pos = a.rowptr[tn] + atomicAdd(&a.cursor[tn], 1);
            a.eids[pos] = a.src[e];
        }
        if (e < N_NODES) {
            if (e == 0) {
                for (int g = 0; g <= a.batch[0]; ++g) a.gstart[g] = 0;
            } else {
                int b0 = a.batch[e - 1], b1 = a.batch[e];
                for (int g = b0 + 1; g <= b1; ++g) a.gstart[g] = e;
            }
            if (e == N_NODES - 1) {
                for (int g = a.batch[e] + 1; g <= N_GRAPHS; ++g) a.gstart[g] = N_NODES;
            }
        }
        publish(&a.ctr[2]);
    } else if (t < NB_HIST + NB_PRE + NB_SCAN + NB_FILL + NB_TILE) {
        // ---------------- layer 0 ------------------------------------------
        wait_count(&a.ctr[2], NB_PRE + NB_FILL);
        const int tile = t - (NB_HIST + NB_PRE + NB_SCAN + NB_FILL);
        mid_phase(smem, tile, a.yA, a.rowptr, a.eids,
                  a.b1_0, a.w2sT0, a.bias2_0, a.w1T1, a.yB, N_NODES, tid);
        publish(&a.ctr[4]);
    } else if (t < NB_HIST + NB_PRE + NB_SCAN + NB_FILL + 2 * NB_TILE) {
        // ---------------- layer 1 ------------------------------------------
        wait_count(&a.ctr[4], NB_TILE);
        const int tile = t - (NB_HIST + NB_PRE + NB_SCAN + NB_FILL + NB_TILE);
        mid_phase(smem, tile, a.yB, a.rowptr, a.eids,
                  a.b1_1, a.w2sT1, a.bias2_1, a.w1T2, a.yA, N_NODES, tid);
        publish(&a.ctr[5]);
    } else {
        // ---------------- layer 2 + pool -----------------------------------
        wait_count(&a.ctr[5], NB_TILE);
        const int tile = t - (NB_HIST + NB_PRE + NB_SCAN + NB_FILL + 2 * NB_TILE);
        final_phase(smem, tile, a.yA, a.rowptr, a.eids,
                    a.b1_2, a.w2sT2, a.bias2_2, a.batch, a.gstart, a.out,
                    N_NODES, tid);
    }
}

// ---------------------------------------------------------------------------
static inline int cdiv_l(long a, int b) { return (int)((a + b - 1) / b); }

extern "C" void kernel_launch(void* const* d_in, const int* in_sizes, int n_in,
                              void* d_out, int out_size, void* d_ws, size_t ws_size,
                              hipStream_t stream) {
    const float* x     = (const float*)d_in[0];
    const int*   ei    = (const int*)d_in[1];
    const int*   src   = ei;
    const int*   dst   = ei + N_EDGES;
    const int*   batch = (const int*)d_in[2];

    const float* P[3][8];
    int p = 3;
    for (int l = 0; l < 3; ++l)
        for (int q = 0; q < 8; ++q)
            P[l][q] = (const float*)d_in[p++];

    const long NP = N_NODES + 128;
    char* wsb   = (char*)d_ws;
    bf16_t* yA  = (bf16_t*)wsb;                       // NP*64 bf16 (ping)
    bf16_t* yB  = yA + NP * 64;                       // NP*64 bf16 (pong)
    float* q    = (float*)(yB + NP * 64);
    float* w1T[3], *w2sT[3], *bias2[3];
    for (int l = 0; l < 3; ++l) {
        w1T[l] = q;   q += 64 * 128;
        w2sT[l] = q;  q += 96 * 64;
        bias2[l] = q; q += 96;
    }
    int* gstart   = (int*)q;
    int* deg      = gstart + 72;
    int* cursor   = deg + N_NODES;
    int* agg      = cursor + N_NODES;   // scan aggregates (256, init -1)
    int* ctr      = agg + 256;          // phase counters (16, init 0)
    int* rowptr   = ctr + 16;
    int* eids     = rowptr + (N_NODES + 1);

    const int B = 256;
    const int DIN[3]  = {128, 64, 64};
    const int DOUT[3] = {64, 64, 96};

    // ---- prep (zero deg/cursor/d_out, init agg/ctr, fold weights) ----
    PrepAll pa;
    for (int l = 0; l < 3; ++l) {
        pa.l[l].w1 = P[l][0]; pa.l[l].w2 = P[l][2]; pa.l[l].b2 = P[l][3];
        pa.l[l].g = P[l][4];  pa.l[l].bb = P[l][5]; pa.l[l].m = P[l][6];
        pa.l[l].v = P[l][7];
        pa.l[l].w1T = w1T[l]; pa.l[l].w2sT = w2sT[l]; pa.l[l].bias2 = bias2[l];
        pa.l[l].DIN = DIN[l]; pa.l[l].DOUT = DOUT[l];
    }
    dim3 pgrid(cdiv_l(64 * 128 + 96 * 64 + 96, B), 3);
    prep_all_kernel<<<pgrid, B, 0, stream>>>(pa, deg, cursor, (float*)d_out, agg, ctr);

    // ---- everything else: ONE ticket-gated dispatch ----
    MegaArgs a;
    a.src = src; a.dst = dst; a.batch = batch; a.x = x;
    a.deg = deg; a.cursor = cursor; a.rowptr = rowptr; a.eids = eids;
    a.gstart = gstart; a.agg = agg; a.ctr = ctr;
    a.yA = yA; a.yB = yB;
    a.w1T0 = w1T[0];
    a.b1_0 = P[0][1]; a.w2sT0 = w2sT[0]; a.bias2_0 = bias2[0]; a.w1T1 = w1T[1];
    a.b1_1 = P[1][1]; a.w2sT1 = w2sT[1]; a.bias2_1 = bias2[1]; a.w1T2 = w1T[2];
    a.b1_2 = P[2][1]; a.w2sT2 = w2sT[2]; a.bias2_2 = bias2[2];
    a.out = (float*)d_out;

    const int total_blocks = NB_HIST + NB_PRE + NB_SCAN + NB_FILL + 3 * NB_TILE;
    mega_kernel<<<total_blocks, 512, 0, stream>>>(a);
}

// Round 9
// 1007.054 us; speedup vs baseline: 2.5176x; 2.5176x over previous
//
#include <hip/hip_runtime.h>

#define N_NODES 100000
#define N_GRAPHS 64
#define N_EDGES 600000
#define BN_EPS 1e-5f

#define NCHUNK 196    // ceil(100001/512) scan chunks
#define NFILLC 1172   // ceil(600000/512) hist/fill chunks
#define NTILE  1563   // ceil(100000/64) node tiles
#define BAR_SLOTS 32

typedef unsigned short bf16_t;

__device__ __forceinline__ unsigned short f2bf(float f) {
    unsigned int u = __float_as_uint(f);
    u += 0x7FFF + ((u >> 16) & 1);
    return (unsigned short)(u >> 16);
}
__device__ __forceinline__ uint2 pack4(float a, float b, float c, float d) {
    uint2 p;
    p.x = (unsigned)f2bf(a) | ((unsigned)f2bf(b) << 16);
    p.y = (unsigned)f2bf(c) | ((unsigned)f2bf(d) << 16);
    return p;
}
__device__ __forceinline__ void bf8_acc(uint4 q, float* acc) {
    acc[0] += __uint_as_float(q.x << 16);
    acc[1] += __uint_as_float(q.x & 0xFFFF0000u);
    acc[2] += __uint_as_float(q.y << 16);
    acc[3] += __uint_as_float(q.y & 0xFFFF0000u);
    acc[4] += __uint_as_float(q.z << 16);
    acc[5] += __uint_as_float(q.z & 0xFFFF0000u);
    acc[6] += __uint_as_float(q.w << 16);
    acc[7] += __uint_as_float(q.w & 0xFFFF0000u);
}

// ---------------------------------------------------------------------------
// One-shot all-participate grid barrier (split arrival counters).
// Safe because grid <= co-resident capacity (occupancy-sized at launch).
// Layout per barrier id: 64 ints; [0..31] slot counters, [32] master, [33] flag.
// ---------------------------------------------------------------------------
__device__ __forceinline__ void gridbar(int* bar, int id, int nblk, int tid) {
    int* B = bar + id * 64;
    __syncthreads();
    __threadfence();
    if (tid == 0) {
        int slot = blockIdx.x & (BAR_SLOTS - 1);
        int expect = nblk / BAR_SLOTS + (((nblk % BAR_SLOTS) > slot) ? 1 : 0);
        int got = atomicAdd(&B[slot], 1) + 1;
        if (got == expect) {
            int nslots = (nblk < BAR_SLOTS) ? nblk : BAR_SLOTS;
            int m = atomicAdd(&B[32], 1) + 1;
            if (m == nslots) atomicExch(&B[33], 1);
        }
        while (atomicAdd(&B[33], 0) == 0) __builtin_amdgcn_s_sleep(32);
    }
    __syncthreads();
    __threadfence();
}

// ---------------------------------------------------------------------------
// Gather one 64-node tile into LDS (stride SS), bias+ReLU applied.
// R3-proven form: 512 threads, 8 lanes/node, unroll-4 + scalar tail.
// ---------------------------------------------------------------------------
template <int SS>
__device__ __forceinline__ void gather_tile_to_lds512(
    const bf16_t* __restrict__ y, const int* __restrict__ rowptr,
    const int* __restrict__ eids, const float* __restrict__ b1,
    float* sT, long base, int tid) {
    const uint4* yv = (const uint4*)y;
    const int f = tid & 7;
    const int lr = tid >> 3;
    float4 b0 = ((const float4*)b1)[f * 2];
    float4 b1v = ((const float4*)b1)[f * 2 + 1];
    long node = base + lr;
    float* sp = &sT[lr * SS + f * 8];
    if (node < N_NODES) {
        float acc[8] = {};
        bf8_acc(yv[node * 8 + f], acc);
        int bgn = rowptr[node], end = rowptr[node + 1];
        int i = bgn;
        for (; i + 3 < end; i += 4) {
            int s0 = eids[i], s1 = eids[i + 1], s2 = eids[i + 2], s3 = eids[i + 3];
            uint4 q0 = yv[(long)s0 * 8 + f];
            uint4 q1 = yv[(long)s1 * 8 + f];
            uint4 q2 = yv[(long)s2 * 8 + f];
            uint4 q3 = yv[(long)s3 * 8 + f];
            bf8_acc(q0, acc); bf8_acc(q1, acc); bf8_acc(q2, acc); bf8_acc(q3, acc);
        }
        for (; i < end; ++i) bf8_acc(yv[(long)eids[i] * 8 + f], acc);
        float4 o0, o1;
        o0.x = fmaxf(acc[0] + b0.x, 0.0f);
        o0.y = fmaxf(acc[1] + b0.y, 0.0f);
        o0.z = fmaxf(acc[2] + b0.z, 0.0f);
        o0.w = fmaxf(acc[3] + b0.w, 0.0f);
        o1.x = fmaxf(acc[4] + b1v.x, 0.0f);
        o1.y = fmaxf(acc[5] + b1v.y, 0.0f);
        o1.z = fmaxf(acc[6] + b1v.z, 0.0f);
        o1.w = fmaxf(acc[7] + b1v.w, 0.0f);
        *(float4*)sp = o0;
        *(float4*)(sp + 4) = o1;
    } else {
        float4 z = {0.0f, 0.0f, 0.0f, 0.0f};
        *(float4*)sp = z;
        *(float4*)(sp + 4) = z;
    }
}

// ---------------------------------------------------------------------------
struct PhArgs {
    const int *src, *dst, *batch;
    const float* x;
    const float *w1r[3], *w2r[3], *b2r[3], *gr[3], *bbr[3], *mr[3], *vr[3], *b1r[3];
    float *w1T[3], *w2sT[3], *bias2[3];
    int *deg, *cursor, *rowptr, *eids, *gstart, *aggA, *chunkoff, *bar;
    bf16_t *yA, *yB, *yC;
    float* out;
};

__global__ __launch_bounds__(512, 6)
void phased_kernel(PhArgs a, int nblk) {
    __shared__ float smem[12544];   // 50176 B union pool
    const int tid = threadIdx.x;
    const int gtid = blockIdx.x * 512 + tid;
    const int gsz = gridDim.x * 512;

    // ============ P0: init + weight fold (verbatim prep math) ============
    for (int i = gtid; i < N_NODES; i += gsz) { a.deg[i] = 0; a.cursor[i] = 0; }
    for (int i = gtid; i < N_GRAPHS * 96; i += gsz) a.out[i] = 0.0f;
    {
        const int DIN[3] = {128, 64, 64}, DOUT[3] = {64, 64, 96};
        for (int l = 0; l < 3; ++l) {
            for (int i = gtid; i < 64 * DIN[l]; i += gsz) {
                int j = i / DIN[l], k = i % DIN[l];
                a.w1T[l][i] = a.w1r[l][k * 64 + j];
            }
            for (int i = gtid; i < DOUT[l] * 64; i += gsz) {
                int c = i / 64, j = i % 64;
                float s = a.gr[l][c] * rsqrtf(a.vr[l][c] + BN_EPS);
                a.w2sT[l][i] = a.w2r[l][j * DOUT[l] + c] * s;
            }
            for (int i = gtid; i < DOUT[l]; i += gsz) {
                float s = a.gr[l][i] * rsqrtf(a.vr[l][i] + BN_EPS);
                a.bias2[l][i] = (a.b2r[l][i] - a.mr[l][i]) * s + a.bbr[l][i];
            }
        }
    }
    gridbar(a.bar, 0, nblk, tid);

    // ============ P1: degree histogram ============
    for (int e = gtid; e < N_EDGES; e += gsz) atomicAdd(&a.deg[a.dst[e]], 1);
    gridbar(a.bar, 1, nblk, tid);

    // ============ P2a: per-chunk local exclusive scan ============
    {
        int* s = (int*)smem;
        for (int c = blockIdx.x; c < NCHUNK; c += gridDim.x) {
            int i = c * 512 + tid;
            int v = (i < N_NODES) ? atomicAdd(&a.deg[i], 0) : 0;  // coherent read
            s[tid] = v;
            __syncthreads();
            for (int off = 1; off < 512; off <<= 1) {
                int tv = (tid >= off) ? s[tid - off] : 0;
                __syncthreads();
                s[tid] += tv;
                __syncthreads();
            }
            if (i <= N_NODES) a.rowptr[i] = s[tid] - v;   // local exclusive
            if (tid == 511) a.aggA[c] = s[511];
            __syncthreads();
        }
    }
    gridbar(a.bar, 2, nblk, tid);
    // ============ P2b: chunk-offset scan (block 0, serial 196 adds) ============
    if (blockIdx.x == 0 && tid == 0) {
        int run = 0;
        for (int c = 0; c < NCHUNK; ++c) { a.chunkoff[c] = run; run += a.aggA[c]; }
    }
    gridbar(a.bar, 3, nblk, tid);
    // ============ P2c: apply offsets (SAME block as P2a -> no cross-XCD RMW) ==
    for (int c = blockIdx.x; c < NCHUNK; c += gridDim.x) {
        int i = c * 512 + tid;
        int off = a.chunkoff[c];
        if (i < N_NODES) a.rowptr[i] += off;
        else if (i == N_NODES) a.rowptr[N_NODES] = N_EDGES;
    }
    gridbar(a.bar, 4, nblk, tid);

    // ============ P3: CSR fill (then) pre-GEMM — natural overlap ============
    for (int c = blockIdx.x; c < NFILLC; c += gridDim.x) {
        int e = c * 512 + tid;
        if (e < N_EDGES) {
            int t = a.dst[e];
            int pos = a.rowptr[t] + atomicAdd(&a.cursor[t], 1);
            a.eids[pos] = a.src[e];
        }
        if (e < N_NODES) {
            if (e == 0) {
                for (int g = 0; g <= a.batch[0]; ++g) a.gstart[g] = 0;
            } else {
                int b0 = a.batch[e - 1], b1 = a.batch[e];
                for (int g = b0 + 1; g <= b1; ++g) a.gstart[g] = e;
            }
            if (e == N_NODES - 1) {
                for (int g = a.batch[e] + 1; g <= N_GRAPHS; ++g) a.gstart[g] = N_NODES;
            }
        }
    }
    // pre: y = x @ W1_0, weights preloaded ONCE (R3 math, 2 rows/thread)
    {
        float* w1s = smem;  // 8192 floats
        const float4* gw1 = (const float4*)a.w1T[0];
        for (int i4 = tid; i4 < 16 * 128; i4 += 512) {
            int row = i4 >> 5, k4 = i4 & 31;
            *(float4*)&w1s[row * 128 + ((k4 ^ ((row >> 2) & 7)) << 2)] = gw1[i4];
        }
        __syncthreads();
        const int jg = tid & 15, ng = tid >> 4, xw = jg & 7;
        const float* wp = &w1s[(jg * 4) * 128];
        const float4* xv = (const float4*)a.x;
        for (int t = blockIdx.x; t < NTILE; t += gridDim.x) {
            const long base = (long)t * 64;
            long r[2];
            #pragma unroll
            for (int i = 0; i < 2; ++i) {
                long rr = base + ng * 2 + i;
                r[i] = (rr < N_NODES) ? rr : (N_NODES - 1);
            }
            float acc[2][4] = {};
            #pragma unroll 4
            for (int k4 = 0; k4 < 32; ++k4) {
                const int ko = (k4 ^ xw) << 2;
                float4 w0 = *(const float4*)&wp[0 * 128 + ko];
                float4 w1v = *(const float4*)&wp[1 * 128 + ko];
                float4 w2v = *(const float4*)&wp[2 * 128 + ko];
                float4 w3v = *(const float4*)&wp[3 * 128 + ko];
                #pragma unroll
                for (int i = 0; i < 2; ++i) {
                    float4 av = xv[r[i] * 32 + k4];
                    acc[i][0] = fmaf(av.x, w0.x, fmaf(av.y, w0.y, fmaf(av.z, w0.z, fmaf(av.w, w0.w, acc[i][0]))));
                    acc[i][1] = fmaf(av.x, w1v.x, fmaf(av.y, w1v.y, fmaf(av.z, w1v.z, fmaf(av.w, w1v.w, acc[i][1]))));
                    acc[i][2] = fmaf(av.x, w2v.x, fmaf(av.y, w2v.y, fmaf(av.z, w2v.z, fmaf(av.w, w2v.w, acc[i][2]))));
                    acc[i][3] = fmaf(av.x, w3v.x, fmaf(av.y, w3v.y, fmaf(av.z, w3v.z, fmaf(av.w, w3v.w, acc[i][3]))));
                }
            }
            #pragma unroll
            for (int i = 0; i < 2; ++i) {
                long n = base + ng * 2 + i;
                if (n < N_NODES) {
                    *(uint2*)(a.yA + n * 64 + jg * 4) = pack4(acc[i][0], acc[i][1], acc[i][2], acc[i][3]);
                }
            }
        }
    }
    gridbar(a.bar, 5, nblk, tid);

    // ============ P4/P5: mid layers (weights preloaded once per block) ======
    #pragma unroll 1
    for (int layer = 0; layer < 2; ++layer) {
        constexpr int SS = 68;
        float* sT = smem;               // 4352
        float* wA = smem + 4352;        // 4096 (w2s, swizzled)
        float* wB = smem + 8448;        // 4096 (w1next, swizzled)
        const bf16_t* yin = (layer == 0) ? a.yA : a.yB;
        bf16_t* yout = (layer == 0) ? a.yB : a.yC;
        const float* b1 = a.b1r[layer];
        const float* bias2 = a.bias2[layer];
        {
            const float4* gw2 = (const float4*)a.w2sT[layer];
            const float4* gw1n = (const float4*)a.w1T[layer + 1];
            for (int i4 = tid; i4 < 16 * 64; i4 += 512) {
                int row = i4 >> 4, k4 = i4 & 15;
                int sw = row * 64 + ((k4 ^ ((row >> 2) & 7)) << 2);
                *(float4*)&wA[sw] = gw2[i4];
                *(float4*)&wB[sw] = gw1n[i4];
            }
        }
        __syncthreads();
        const int jg = tid & 15, ng = tid >> 4, xw = jg & 7;
        for (int t = blockIdx.x; t < NTILE; t += gridDim.x) {
            const long base = (long)t * 64;
            gather_tile_to_lds512<SS>(yin, a.rowptr, a.eids, b1, sT, base, tid);
            __syncthreads();
            float h[2][4];
            {
                const float* wp = &wA[(jg * 4) * 64];
                float acc[2][4] = {};
                #pragma unroll 4
                for (int k4 = 0; k4 < 16; ++k4) {
                    const int ko = (k4 ^ xw) << 2;
                    float4 w0 = *(const float4*)&wp[0 * 64 + ko];
                    float4 w1v = *(const float4*)&wp[1 * 64 + ko];
                    float4 w2v = *(const float4*)&wp[2 * 64 + ko];
                    float4 w3v = *(const float4*)&wp[3 * 64 + ko];
                    #pragma unroll
                    for (int i = 0; i < 2; ++i) {
                        float4 av = *(const float4*)&sT[(ng * 2 + i) * SS + k4 * 4];
                        acc[i][0] = fmaf(av.x, w0.x, fmaf(av.y, w0.y, fmaf(av.z, w0.z, fmaf(av.w, w0.w, acc[i][0]))));
                        acc[i][1] = fmaf(av.x, w1v.x, fmaf(av.y, w1v.y, fmaf(av.z, w1v.z, fmaf(av.w, w1v.w, acc[i][1]))));
                        acc[i][2] = fmaf(av.x, w2v.x, fmaf(av.y, w2v.y, fmaf(av.z, w2v.z, fmaf(av.w, w2v.w, acc[i][2]))));
                        acc[i][3] = fmaf(av.x, w3v.x, fmaf(av.y, w3v.y, fmaf(av.z, w3v.z, fmaf(av.w, w3v.w, acc[i][3]))));
                    }
                }
                float4 bv = *(const float4*)&bias2[jg * 4];
                #pragma unroll
                for (int i = 0; i < 2; ++i) {
                    h[i][0] = fmaxf(acc[i][0] + bv.x, 0.0f);
                    h[i][1] = fmaxf(acc[i][1] + bv.y, 0.0f);
                    h[i][2] = fmaxf(acc[i][2] + bv.z, 0.0f);
                    h[i][3] = fmaxf(acc[i][3] + bv.w, 0.0f);
                }
            }
            __syncthreads();
            #pragma unroll
            for (int i = 0; i < 2; ++i) {
                float4 hv = {h[i][0], h[i][1], h[i][2], h[i][3]};
                *(float4*)&sT[(ng * 2 + i) * SS + jg * 4] = hv;
            }
            __syncthreads();
            {
                const float* ap = &sT[(ng * 2) * SS];
                const float* wp = &wB[(jg * 4) * 64];
                float acc[2][4] = {};
                #pragma unroll 4
                for (int k4 = 0; k4 < 16; ++k4) {
                    const int ko = (k4 ^ xw) << 2;
                    float4 w0 = *(const float4*)&wp[0 * 64 + ko];
                    float4 w1v = *(const float4*)&wp[1 * 64 + ko];
                    float4 w2v = *(const float4*)&wp[2 * 64 + ko];
                    float4 w3v = *(const float4*)&wp[3 * 64 + ko];
                    #pragma unroll
                    for (int i = 0; i < 2; ++i) {
                        float4 av = *(const float4*)&ap[i * SS + k4 * 4];
                        acc[i][0] = fmaf(av.x, w0.x, fmaf(av.y, w0.y, fmaf(av.z, w0.z, fmaf(av.w, w0.w, acc[i][0]))));
                        acc[i][1] = fmaf(av.x, w1v.x, fmaf(av.y, w1v.y, fmaf(av.z, w1v.z, fmaf(av.w, w1v.w, acc[i][1]))));
                        acc[i][2] = fmaf(av.x, w2v.x, fmaf(av.y, w2v.y, fmaf(av.z, w2v.z, fmaf(av.w, w2v.w, acc[i][2]))));
                        acc[i][3] = fmaf(av.x, w3v.x, fmaf(av.y, w3v.y, fmaf(av.z, w3v.z, fmaf(av.w, w3v.w, acc[i][3]))));
                    }
                }
                #pragma unroll
                for (int i = 0; i < 2; ++i) {
                    long n = base + ng * 2 + i;
                    if (n < N_NODES) {
                        *(uint2*)(yout + n * 64 + jg * 4) = pack4(acc[i][0], acc[i][1], acc[i][2], acc[i][3]);
                    }
                }
            }
            __syncthreads();   // protect sT before next tile's gather
        }
        gridbar(a.bar, 6 + layer, nblk, tid);
    }

    // ============ P6: final layer + mean-pool (per-tile w2s reload) =========
    {
        constexpr int CPT = 6;
        constexpr int SS = 68;
        float* w2s = smem;             // 6144, reused as hbuf[64][96]
        float* tbuf = smem + 6144;     // 4352
        const int cg_ = tid & 15, ng = tid >> 4, xw = cg_ & 7;
        for (int t = blockIdx.x; t < NTILE; t += gridDim.x) {
            const long base = (long)t * 64;
            const float4* gw2 = (const float4*)a.w2sT[2];
            for (int i4 = tid; i4 < 96 * 16; i4 += 512) {
                int row = i4 >> 4, k4 = i4 & 15;
                *(float4*)&w2s[row * 64 + ((k4 ^ ((row / CPT) & 7)) << 2)] = gw2[i4];
            }
            gather_tile_to_lds512<SS>(a.yC, a.rowptr, a.eids, a.b1r[2], tbuf, base, tid);
            __syncthreads();

            const float* wp = &w2s[(cg_ * CPT) * 64];
            float acc[2][CPT] = {};
            #pragma unroll 4
            for (int k4 = 0; k4 < 16; ++k4) {
                const int ko = (k4 ^ xw) << 2;
                float4 wv[CPT];
                #pragma unroll
                for (int c = 0; c < CPT; ++c) wv[c] = *(const float4*)&wp[c * 64 + ko];
                #pragma unroll
                for (int i = 0; i < 2; ++i) {
                    float4 hv = *(const float4*)&tbuf[(ng * 2 + i) * SS + k4 * 4];
                    #pragma unroll
                    for (int c = 0; c < CPT; ++c)
                        acc[i][c] = fmaf(hv.x, wv[c].x, fmaf(hv.y, wv[c].y, fmaf(hv.z, wv[c].z, fmaf(hv.w, wv[c].w, acc[i][c]))));
                }
            }
            float bv[CPT];
            #pragma unroll
            for (int c = 0; c < CPT; ++c) bv[c] = a.bias2[2][cg_ * CPT + c];
            __syncthreads();  // w2s weight reads done; buffer becomes hbuf
            #pragma unroll
            for (int i = 0; i < 2; ++i) {
                long n = base + ng * 2 + i;
                float* hp = &w2s[(ng * 2 + i) * 96 + cg_ * CPT];
                if (n < N_NODES) {
                    #pragma unroll
                    for (int c = 0; c < CPT; ++c) hp[c] = fmaxf(acc[i][c] + bv[c], 0.0f);
                } else {
                    #pragma unroll
                    for (int c = 0; c < CPT; ++c) hp[c] = 0.0f;
                }
            }
            __syncthreads();

            if (tid < 96) {
                int limit = (int)((N_NODES - base < 64) ? (N_NODES - base) : 64);
                int gcur = a.batch[base];
                float s = 0.0f;
                for (int r = 0; r < limit; ++r) {
                    int g = a.batch[base + r];
                    if (g != gcur) {
                        float inv = 1.0f / fmaxf((float)(a.gstart[gcur + 1] - a.gstart[gcur]), 1.0f);
                        atomicAdd(&a.out[gcur * 96 + tid], s * inv);
                        s = 0.0f;
                        gcur = g;
                    }
                    s += w2s[r * 96 + tid];
                }
                float inv = 1.0f / fmaxf((float)(a.gstart[gcur + 1] - a.gstart[gcur]), 1.0f);
                atomicAdd(&a.out[gcur * 96 + tid], s * inv);
            }
            __syncthreads();  // protect w2s/tbuf before next tile
        }
    }
}

// ---------------------------------------------------------------------------
static inline int cdiv_l(long a, int b) { return (int)((a + b - 1) / b); }

extern "C" void kernel_launch(void* const* d_in, const int* in_sizes, int n_in,
                              void* d_out, int out_size, void* d_ws, size_t ws_size,
                              hipStream_t stream) {
    const float* x     = (const float*)d_in[0];
    const int*   ei    = (const int*)d_in[1];
    const int*   src   = ei;
    const int*   dst   = ei + N_EDGES;
    const int*   batch = (const int*)d_in[2];

    const float* P[3][8];
    int p = 3;
    for (int l = 0; l < 3; ++l)
        for (int q = 0; q < 8; ++q)
            P[l][q] = (const float*)d_in[p++];

    const long NP = N_NODES + 128;
    char* wsb   = (char*)d_ws;
    bf16_t* yA  = (bf16_t*)wsb;                       // NP*64 bf16
    bf16_t* yB  = yA + NP * 64;
    bf16_t* yC  = yB + NP * 64;
    float* q    = (float*)(yC + NP * 64);
    float* w1T[3], *w2sT[3], *bias2[3];
    for (int l = 0; l < 3; ++l) {
        w1T[l] = q;   q += 64 * 128;
        w2sT[l] = q;  q += 96 * 64;
        bias2[l] = q; q += 96;
    }
    int* gstart   = (int*)q;
    int* deg      = gstart + 72;
    int* cursor   = deg + N_NODES;
    int* aggA     = cursor + N_NODES;
    int* chunkoff = aggA + 256;
    int* bar      = chunkoff + 256;     // 8 barriers x 64 ints
    int* rowptr   = bar + 8 * 64;
    int* eids     = rowptr + (N_NODES + 1);

    PhArgs a;
    a.src = src; a.dst = dst; a.batch = batch; a.x = x;
    for (int l = 0; l < 3; ++l) {
        a.w1r[l] = P[l][0]; a.b1r[l] = P[l][1]; a.w2r[l] = P[l][2]; a.b2r[l] = P[l][3];
        a.gr[l] = P[l][4];  a.bbr[l] = P[l][5]; a.mr[l] = P[l][6];  a.vr[l] = P[l][7];
        a.w1T[l] = w1T[l];  a.w2sT[l] = w2sT[l]; a.bias2[l] = bias2[l];
    }
    a.deg = deg; a.cursor = cursor; a.rowptr = rowptr; a.eids = eids;
    a.gstart = gstart; a.aggA = aggA; a.chunkoff = chunkoff; a.bar = bar;
    a.yA = yA; a.yB = yB; a.yC = yC;
    a.out = (float*)d_out;

    // grid = guaranteed co-resident capacity (required for gridbar safety)
    static int s_grid = 0;
    if (s_grid == 0) {
        int nb = 0;
        if (hipOccupancyMaxActiveBlocksPerMultiprocessor(&nb, phased_kernel, 512, 0)
                != hipSuccess || nb < 1)
            nb = 1;
        long g = (long)nb * 256;
        if (g > 768) g = 768;           // 3 blocks/CU suffices for all phases
        s_grid = (int)g;
    }
    const int grid = s_grid;

    hipMemsetAsync(bar, 0, 8 * 64 * sizeof(int), stream);
    phased_kernel<<<grid, 512, 0, stream>>>(a, grid);
}

// Round 10
// 353.943 us; speedup vs baseline: 7.1632x; 2.8452x over previous
//
#include <hip/hip_runtime.h>

#define N_NODES 100000
#define N_GRAPHS 64
#define N_EDGES 600000
#define BN_EPS 1e-5f

// XCD-binned fill constants: 2346 fill blocks, groups of 8 -> 293 blocks/group,
// each group scans all edges in chunks of 2048 (293*2048 = 600064 >= N_EDGES).
#define FILL_NSUB 293
#define FILL_PER  2048

typedef unsigned short bf16_t;

__device__ __forceinline__ unsigned short f2bf(float f) {
    unsigned int u = __float_as_uint(f);
    u += 0x7FFF + ((u >> 16) & 1);
    return (unsigned short)(u >> 16);
}
__device__ __forceinline__ uint2 pack4(float a, float b, float c, float d) {
    uint2 p;
    p.x = (unsigned)f2bf(a) | ((unsigned)f2bf(b) << 16);
    p.y = (unsigned)f2bf(c) | ((unsigned)f2bf(d) << 16);
    return p;
}
// accumulate 8 bf16 (uint4) into acc[0..7]
__device__ __forceinline__ void bf8_acc(uint4 q, float* acc) {
    acc[0] += __uint_as_float(q.x << 16);
    acc[1] += __uint_as_float(q.x & 0xFFFF0000u);
    acc[2] += __uint_as_float(q.y << 16);
    acc[3] += __uint_as_float(q.y & 0xFFFF0000u);
    acc[4] += __uint_as_float(q.z << 16);
    acc[5] += __uint_as_float(q.z & 0xFFFF0000u);
    acc[6] += __uint_as_float(q.w << 16);
    acc[7] += __uint_as_float(q.w & 0xFFFF0000u);
}

// Gather one 64-node tile into LDS (stride SS), bias+ReLU applied.
// R3-proven form: 512-thread single pass, 8 lanes/node, unroll-4 + tail.
template <int SS>
__device__ __forceinline__ void gather_tile_to_lds512(
    const bf16_t* __restrict__ y, const int* __restrict__ rowptr,
    const int* __restrict__ eids, const float* __restrict__ b1,
    float* sT, long base, int n_nodes, int tid) {
    const uint4* yv = (const uint4*)y;
    const int f = tid & 7;
    const int lr = tid >> 3;   // local row 0..63
    float4 b0 = ((const float4*)b1)[f * 2];
    float4 b1v = ((const float4*)b1)[f * 2 + 1];
    long node = base + lr;
    float* sp = &sT[lr * SS + f * 8];
    if (node < n_nodes) {
        float acc[8] = {};
        bf8_acc(yv[node * 8 + f], acc);
        int bgn = rowptr[node], end = rowptr[node + 1];
        int i = bgn;
        for (; i + 3 < end; i += 4) {
            int s0 = eids[i], s1 = eids[i + 1], s2 = eids[i + 2], s3 = eids[i + 3];
            uint4 q0 = yv[(long)s0 * 8 + f];
            uint4 q1 = yv[(long)s1 * 8 + f];
            uint4 q2 = yv[(long)s2 * 8 + f];
            uint4 q3 = yv[(long)s3 * 8 + f];
            bf8_acc(q0, acc); bf8_acc(q1, acc); bf8_acc(q2, acc); bf8_acc(q3, acc);
        }
        for (; i < end; ++i) bf8_acc(yv[(long)eids[i] * 8 + f], acc);
        float4 o0, o1;
        o0.x = fmaxf(acc[0] + b0.x, 0.0f);
        o0.y = fmaxf(acc[1] + b0.y, 0.0f);
        o0.z = fmaxf(acc[2] + b0.z, 0.0f);
        o0.w = fmaxf(acc[3] + b0.w, 0.0f);
        o1.x = fmaxf(acc[4] + b1v.x, 0.0f);
        o1.y = fmaxf(acc[5] + b1v.y, 0.0f);
        o1.z = fmaxf(acc[6] + b1v.z, 0.0f);
        o1.w = fmaxf(acc[7] + b1v.w, 0.0f);
        *(float4*)sp = o0;
        *(float4*)(sp + 4) = o1;
    } else {
        float4 z = {0.0f, 0.0f, 0.0f, 0.0f};
        *(float4*)sp = z;
        *(float4*)(sp + 4) = z;
    }
}

// ===========================================================================
// CSR build
// ===========================================================================
__global__ void deg_hist_kernel(const int* __restrict__ dst,
                                int* __restrict__ deg, int n_edges) {
    int e = blockIdx.x * blockDim.x + threadIdx.x;
    if (e < n_edges) atomicAdd(&deg[dst[e]], 1);
}

// One-kernel exclusive scan: per-block scan + aggregate publish (atomicExch
// into -1-initialized slot) + parallel spin-read of predecessors (atomicAdd,
// device-scope => cross-XCD safe). All 98 blocks co-resident.
__global__ __launch_bounds__(1024)
void scan_fused_kernel(const int* __restrict__ deg, int* __restrict__ rowptr,
                       int* __restrict__ agg, int n, int total) {
    __shared__ int s[1024];
    __shared__ int s2[128];
    __shared__ int offset_sh;
    const int b = blockIdx.x;
    const int i = b * 1024 + threadIdx.x;
    int v = (i < n) ? deg[i] : 0;
    s[threadIdx.x] = v;
    __syncthreads();
    for (int off = 1; off < 1024; off <<= 1) {
        int t = (threadIdx.x >= (unsigned)off) ? s[threadIdx.x - off] : 0;
        __syncthreads();
        s[threadIdx.x] += t;
        __syncthreads();
    }
    // publish this block's total (slot pre-initialized to -1 by prep)
    if (threadIdx.x == 1023) atomicExch(&agg[b], s[1023]);
    // threads 0..b-1 spin-read predecessor aggregates
    if (threadIdx.x < b) {
        int val;
        do { val = atomicAdd(&agg[threadIdx.x], 0); } while (val == -1);
        s2[threadIdx.x] = val;
    }
    __syncthreads();
    if (threadIdx.x == 0) {
        int off = 0;
        for (int k = 0; k < b; ++k) off += s2[k];
        offset_sh = off;
    }
    __syncthreads();
    const int off = offset_sh;
    if (i < n) rowptr[i] = off + s[threadIdx.x] - v;
    else if (i == n) rowptr[n] = total;
}

// ===========================================================================
// MERGED fill_bounds + pre_gemm (R11 proven config: 256 threads, 3:2).
// R19: the fill role is XCD-BINNED — fill-block group (fb&7) scans the whole
// edge list (dst reads L3-resident, cheap) but only processes edges whose
// dst lies in its 12500-node range. If blockIdx%8 ~ XCD, each eids/cursor
// cache line is then written by exactly ONE XCD, eliminating the cross-XCD
// partial-line ping-pong behind the 17x eids write amplification (WRITE_SIZE
// 41MB for 2.4MB payload). Each edge is processed exactly once regardless of
// actual XCD placement (partition is by dst value, not placement).
// ===========================================================================
__global__ __launch_bounds__(256)
void fill_pre_kernel(const int* __restrict__ src, const int* __restrict__ dst,
                     const int* __restrict__ rowptr, int* __restrict__ cursor,
                     int* __restrict__ eids, const int* __restrict__ batch,
                     int* __restrict__ gstart,
                     const float* __restrict__ x, const float* __restrict__ w1T,
                     bf16_t* __restrict__ y, int n_edges, int n_nodes) {
    __shared__ float w1s[64 * 128];
    const int bq = blockIdx.x / 5, br = blockIdx.x % 5;

    if (br < 3) {
        // ------------------- fill role (3 of every 5 blocks) -------------------
        const int fb = bq * 3 + br;            // flat fill-block id, 0..2345
        // graph bounds (original flat mapping over nodes)
        int e0 = fb * 256 + threadIdx.x;
        if (e0 < n_nodes) {
            if (e0 == 0) {
                for (int g = 0; g <= batch[0]; ++g) gstart[g] = 0;
            } else {
                int b0 = batch[e0 - 1], b1 = batch[e0];
                for (int g = b0 + 1; g <= b1; ++g) gstart[g] = e0;
            }
            if (e0 == n_nodes - 1) {
                for (int g = batch[e0] + 1; g <= N_GRAPHS; ++g) gstart[g] = n_nodes;
            }
        }
        // XCD-binned eids fill
        const int xcd = fb & 7;
        const int sub = fb >> 3;               // 0..293
        if (sub < FILL_NSUB) {
            const int lo = xcd * (N_NODES / 8);
            const int hi = lo + (N_NODES / 8);
            int beg = sub * FILL_PER;
            int end = beg + FILL_PER;
            if (end > n_edges) end = n_edges;
            for (int e = beg + threadIdx.x; e < end; e += 256) {
                int t = dst[e];
                if (t >= lo && t < hi) {
                    int pos = rowptr[t] + atomicAdd(&cursor[t], 1);
                    eids[pos] = src[e];
                }
            }
        }
        return;
    }

    // ------------------- gemm role (2 of every 5 blocks) -------------------
    const int gb = bq * 2 + (br - 3);
    const long base = (long)gb * 64;
    if (base >= n_nodes) return;
    const int tid = threadIdx.x;

    const float4* gw1 = (const float4*)w1T;
    for (int i4 = tid; i4 < 16 * 128; i4 += 256) {
        int row = i4 >> 5, k4 = i4 & 31;
        *(float4*)&w1s[row * 128 + ((k4 ^ ((row >> 2) & 7)) << 2)] = gw1[i4];
    }
    __syncthreads();

    const int jg = tid & 15, ng = tid >> 4, xw = jg & 7;
    const float* wp = &w1s[(jg * 4) * 128];
    const float4* xv = (const float4*)x;
    long r[4];
    #pragma unroll
    for (int i = 0; i < 4; ++i) {
        long rr = base + ng * 4 + i;
        r[i] = (rr < n_nodes) ? rr : (n_nodes - 1);  // clamp: x has no padding
    }
    float acc[4][4] = {};
    #pragma unroll 4
    for (int k4 = 0; k4 < 32; ++k4) {
        const int ko = (k4 ^ xw) << 2;
        float4 w0 = *(const float4*)&wp[0 * 128 + ko];
        float4 w1v = *(const float4*)&wp[1 * 128 + ko];
        float4 w2v = *(const float4*)&wp[2 * 128 + ko];
        float4 w3v = *(const float4*)&wp[3 * 128 + ko];
        #pragma unroll
        for (int i = 0; i < 4; ++i) {
            float4 a = xv[r[i] * 32 + k4];
            acc[i][0] = fmaf(a.x, w0.x, fmaf(a.y, w0.y, fmaf(a.z, w0.z, fmaf(a.w, w0.w, acc[i][0]))));
            acc[i][1] = fmaf(a.x, w1v.x, fmaf(a.y, w1v.y, fmaf(a.z, w1v.z, fmaf(a.w, w1v.w, acc[i][1]))));
            acc[i][2] = fmaf(a.x, w2v.x, fmaf(a.y, w2v.y, fmaf(a.z, w2v.z, fmaf(a.w, w2v.w, acc[i][2]))));
            acc[i][3] = fmaf(a.x, w3v.x, fmaf(a.y, w3v.y, fmaf(a.z, w3v.z, fmaf(a.w, w3v.w, acc[i][3]))));
        }
    }
    #pragma unroll
    for (int i = 0; i < 4; ++i) {
        long n = base + ng * 4 + i;
        if (n < n_nodes) {
            *(uint2*)(y + n * 64 + jg * 4) = pack4(acc[i][0], acc[i][1], acc[i][2], acc[i][3]);
        }
    }
}

// ===========================================================================
// Prep (blockIdx.y = layer); y==0 blocks also zero deg/cursor/d_out and
// init scan aggregates to -1.
// ===========================================================================
struct LayerPrep {
    const float *w1, *w2, *b2, *g, *bb, *m, *v;
    float *w1T, *w2sT, *bias2;
    int DIN, DOUT;
};
struct PrepAll { LayerPrep l[3]; };

__global__ void prep_all_kernel(PrepAll pa, int* __restrict__ deg,
                                int* __restrict__ cursor, float* __restrict__ out_zero,
                                int* __restrict__ agg) {
    LayerPrep P = pa.l[blockIdx.y];
    int i = blockIdx.x * blockDim.x + threadIdx.x;
    if (blockIdx.y == 0) {
        int stride = gridDim.x * blockDim.x;
        for (int k = i; k < N_NODES; k += stride) { deg[k] = 0; cursor[k] = 0; }
        for (int k = i; k < N_GRAPHS * 96; k += stride) out_zero[k] = 0.0f;
        if (i < 128) agg[i] = -1;
    }
    if (i < 64 * P.DIN) {
        int j = i / P.DIN, k = i % P.DIN;
        P.w1T[i] = P.w1[k * 64 + j];
    }
    int i2 = i - 64 * P.DIN;
    if (i2 >= 0 && i2 < P.DOUT * 64) {
        int c = i2 / 64, j = i2 % 64;
        float s = P.g[c] * rsqrtf(P.v[c] + BN_EPS);
        P.w2sT[i2] = P.w2[j * P.DOUT + c] * s;
    }
    int i3 = i2 - P.DOUT * 64;
    if (i3 >= 0 && i3 < P.DOUT) {
        float s = P.g[i3] * rsqrtf(P.v[i3] + BN_EPS);
        P.bias2[i3] = (P.b2[i3] - P.m[i3]) * s + P.bb[i3];
    }
}

// ===========================================================================
// FUSED gather + mid layer (R13-proven: 512 threads, 2 rows/thread GEMMs).
// ===========================================================================
__global__ __launch_bounds__(512)
void fused_gather_mid_kernel(const bf16_t* __restrict__ y,
                             const int* __restrict__ rowptr,
                             const int* __restrict__ eids,
                             const float* __restrict__ b1,
                             const float* __restrict__ w2sT,
                             const float* __restrict__ bias2,
                             const float* __restrict__ w1nT,
                             bf16_t* __restrict__ ynext, int n_nodes) {
    constexpr int SS = 68;
    __shared__ float sT[64 * SS];
    __shared__ float wbuf[64 * 64];
    const int tid = threadIdx.x;
    const long base = (long)blockIdx.x * 64;

    const float4* gw2 = (const float4*)w2sT;
    for (int i4 = tid; i4 < 16 * 64; i4 += 512) {
        int row = i4 >> 4, k4 = i4 & 15;
        *(float4*)&wbuf[row * 64 + ((k4 ^ ((row >> 2) & 7)) << 2)] = gw2[i4];
    }
    // gather phase (the expensive, latency-bound part)
    gather_tile_to_lds512<SS>(y, rowptr, eids, b1, sT, base, n_nodes, tid);
    __syncthreads();

    const int jg = tid & 15, ng = tid >> 4, xw = jg & 7;  // ng 0..31, 2 rows each

    float h[2][4];
    {
        const float* wp = &wbuf[(jg * 4) * 64];
        float acc[2][4] = {};
        #pragma unroll 4
        for (int k4 = 0; k4 < 16; ++k4) {
            const int ko = (k4 ^ xw) << 2;
            float4 w0 = *(const float4*)&wp[0 * 64 + ko];
            float4 w1v = *(const float4*)&wp[1 * 64 + ko];
            float4 w2v = *(const float4*)&wp[2 * 64 + ko];
            float4 w3v = *(const float4*)&wp[3 * 64 + ko];
            #pragma unroll
            for (int i = 0; i < 2; ++i) {
                float4 a = *(const float4*)&sT[(ng * 2 + i) * SS + k4 * 4];
                acc[i][0] = fmaf(a.x, w0.x, fmaf(a.y, w0.y, fmaf(a.z, w0.z, fmaf(a.w, w0.w, acc[i][0]))));
                acc[i][1] = fmaf(a.x, w1v.x, fmaf(a.y, w1v.y, fmaf(a.z, w1v.z, fmaf(a.w, w1v.w, acc[i][1]))));
                acc[i][2] = fmaf(a.x, w2v.x, fmaf(a.y, w2v.y, fmaf(a.z, w2v.z, fmaf(a.w, w2v.w, acc[i][2]))));
                acc[i][3] = fmaf(a.x, w3v.x, fmaf(a.y, w3v.y, fmaf(a.z, w3v.z, fmaf(a.w, w3v.w, acc[i][3]))));
            }
        }
        float4 bv = *(const float4*)&bias2[jg * 4];
        #pragma unroll
        for (int i = 0; i < 2; ++i) {
            h[i][0] = fmaxf(acc[i][0] + bv.x, 0.0f);
            h[i][1] = fmaxf(acc[i][1] + bv.y, 0.0f);
            h[i][2] = fmaxf(acc[i][2] + bv.z, 0.0f);
            h[i][3] = fmaxf(acc[i][3] + bv.w, 0.0f);
        }
    }
    __syncthreads();

    #pragma unroll
    for (int i = 0; i < 2; ++i) {
        float4 hv = {h[i][0], h[i][1], h[i][2], h[i][3]};
        *(float4*)&sT[(ng * 2 + i) * SS + jg * 4] = hv;
    }
    const float4* gw1n = (const float4*)w1nT;
    for (int i4 = tid; i4 < 16 * 64; i4 += 512) {
        int row = i4 >> 4, k4 = i4 & 15;
        *(float4*)&wbuf[row * 64 + ((k4 ^ ((row >> 2) & 7)) << 2)] = gw1n[i4];
    }
    __syncthreads();

    {
        const float* ap = &sT[(ng * 2) * SS];
        const float* wp = &wbuf[(jg * 4) * 64];
        float acc[2][4] = {};
        #pragma unroll 4
        for (int k4 = 0; k4 < 16; ++k4) {
            const int ko = (k4 ^ xw) << 2;
            float4 w0 = *(const float4*)&wp[0 * 64 + ko];
            float4 w1v = *(const float4*)&wp[1 * 64 + ko];
            float4 w2v = *(const float4*)&wp[2 * 64 + ko];
            float4 w3v = *(const float4*)&wp[3 * 64 + ko];
            #pragma unroll
            for (int i = 0; i < 2; ++i) {
                float4 a = *(const float4*)&ap[i * SS + k4 * 4];
                acc[i][0] = fmaf(a.x, w0.x, fmaf(a.y, w0.y, fmaf(a.z, w0.z, fmaf(a.w, w0.w, acc[i][0]))));
                acc[i][1] = fmaf(a.x, w1v.x, fmaf(a.y, w1v.y, fmaf(a.z, w1v.z, fmaf(a.w, w1v.w, acc[i][1]))));
                acc[i][2] = fmaf(a.x, w2v.x, fmaf(a.y, w2v.y, fmaf(a.z, w2v.z, fmaf(a.w, w2v.w, acc[i][2]))));
                acc[i][3] = fmaf(a.x, w3v.x, fmaf(a.y, w3v.y, fmaf(a.z, w3v.z, fmaf(a.w, w3v.w, acc[i][3]))));
            }
        }
        #pragma unroll
        for (int i = 0; i < 2; ++i) {
            long n = base + ng * 2 + i;
            if (n < n_nodes) {
                *(uint2*)(ynext + n * 64 + jg * 4) = pack4(acc[i][0], acc[i][1], acc[i][2], acc[i][3]);
            }
        }
    }
}

// ===========================================================================
// FUSED gather + final layer + mean-pool (R13-proven: 512 threads).
// ===========================================================================
__global__ __launch_bounds__(512)
void fused_gather_final_kernel(const bf16_t* __restrict__ y,
                               const int* __restrict__ rowptr,
                               const int* __restrict__ eids,
                               const float* __restrict__ b1,
                               const float* __restrict__ w2sT,
                               const float* __restrict__ bias2,
                               const int* __restrict__ batch,
                               const int* __restrict__ gstart,
                               float* __restrict__ out, int n_nodes) {
    constexpr int CPT = 6;
    constexpr int SS = 68;
    __shared__ float w2s[96 * 64];  // later reused as hbuf[64][96]
    __shared__ float tbuf[64 * SS];
    const int tid = threadIdx.x;
    const long base = (long)blockIdx.x * 64;

    const float4* gw2 = (const float4*)w2sT;
    for (int i4 = tid; i4 < 96 * 16; i4 += 512) {
        int row = i4 >> 4, k4 = i4 & 15;
        *(float4*)&w2s[row * 64 + ((k4 ^ ((row / CPT) & 7)) << 2)] = gw2[i4];
    }
    // gather phase
    gather_tile_to_lds512<SS>(y, rowptr, eids, b1, tbuf, base, n_nodes, tid);
    __syncthreads();

    const int cg_ = tid & 15, ng = tid >> 4, xw = cg_ & 7;  // ng 0..31
    const float* wp = &w2s[(cg_ * CPT) * 64];
    float acc[2][CPT] = {};
    #pragma unroll 4
    for (int k4 = 0; k4 < 16; ++k4) {
        const int ko = (k4 ^ xw) << 2;
        float4 wv[CPT];
        #pragma unroll
        for (int c = 0; c < CPT; ++c) wv[c] = *(const float4*)&wp[c * 64 + ko];
        #pragma unroll
        for (int i = 0; i < 2; ++i) {
            float4 h = *(const float4*)&tbuf[(ng * 2 + i) * SS + k4 * 4];
            #pragma unroll
            for (int c = 0; c < CPT; ++c)
                acc[i][c] = fmaf(h.x, wv[c].x, fmaf(h.y, wv[c].y, fmaf(h.z, wv[c].z, fmaf(h.w, wv[c].w, acc[i][c]))));
        }
    }
    float bv[CPT];
    #pragma unroll
    for (int c = 0; c < CPT; ++c) bv[c] = bias2[cg_ * CPT + c];
    __syncthreads();  // all w2s weight reads done; buffer becomes hbuf
    #pragma unroll
    for (int i = 0; i < 2; ++i) {
        long n = base + ng * 2 + i;
        float* hp = &w2s[(ng * 2 + i) * 96 + cg_ * CPT];
        if (n < n_nodes) {
            #pragma unroll
            for (int c = 0; c < CPT; ++c) hp[c] = fmaxf(acc[i][c] + bv[c], 0.0f);
        } else {
            #pragma unroll
            for (int c = 0; c < CPT; ++c) hp[c] = 0.0f;
        }
    }
    __syncthreads();

    // per-graph column sums over this block's 64 sorted rows
    if (tid < 96) {
        int limit = (int)((n_nodes - base < 64) ? (n_nodes - base) : 64);
        int gcur = batch[base];
        float s = 0.0f;
        for (int r = 0; r < limit; ++r) {
            int g = batch[base + r];
            if (g != gcur) {
                float inv = 1.0f / fmaxf((float)(gstart[gcur + 1] - gstart[gcur]), 1.0f);
                atomicAdd(&out[gcur * 96 + tid], s * inv);
                s = 0.0f;
                gcur = g;
            }
            s += w2s[r * 96 + tid];
        }
        float inv = 1.0f / fmaxf((float)(gstart[gcur + 1] - gstart[gcur]), 1.0f);
        atomicAdd(&out[gcur * 96 + tid], s * inv);
    }
}

// ---------------------------------------------------------------------------
static inline int cdiv_l(long a, int b) { return (int)((a + b - 1) / b); }

extern "C" void kernel_launch(void* const* d_in, const int* in_sizes, int n_in,
                              void* d_out, int out_size, void* d_ws, size_t ws_size,
                              hipStream_t stream) {
    const float* x     = (const float*)d_in[0];
    const int*   ei    = (const int*)d_in[1];
    const int*   src   = ei;
    const int*   dst   = ei + N_EDGES;
    const int*   batch = (const int*)d_in[2];

    const float* P[3][8];
    int p = 3;
    for (int l = 0; l < 3; ++l)
        for (int q = 0; q < 8; ++q)
            P[l][q] = (const float*)d_in[p++];

    const long NP = N_NODES + 128;
    char* wsb   = (char*)d_ws;
    bf16_t* yA  = (bf16_t*)wsb;                       // NP*64 bf16 (ping)
    bf16_t* yB  = yA + NP * 64;                       // NP*64 bf16 (pong)
    float* q    = (float*)(yB + NP * 64);
    float* w1T[3], *w2sT[3], *bias2[3];
    for (int l = 0; l < 3; ++l) {
        w1T[l] = q;   q += 64 * 128;
        w2sT[l] = q;  q += 96 * 64;
        bias2[l] = q; q += 96;
    }
    int* gstart   = (int*)q;
    int* deg      = gstart + 72;
    int* cursor   = deg + N_NODES;
    int* partials = cursor + N_NODES;   // scan aggregates (init -1)
    int* rowptr   = partials + 128;
    int* eids     = rowptr + (N_NODES + 1);

    const int B = 256;
    const int DIN[3]  = {128, 64, 64};
    const int DOUT[3] = {64, 64, 96};

    // ---- prep (zero deg/cursor/d_out, init scan slots, fold weights) ----
    PrepAll pa;
    for (int l = 0; l < 3; ++l) {
        pa.l[l].w1 = P[l][0]; pa.l[l].w2 = P[l][2]; pa.l[l].b2 = P[l][3];
        pa.l[l].g = P[l][4];  pa.l[l].bb = P[l][5]; pa.l[l].m = P[l][6];
        pa.l[l].v = P[l][7];
        pa.l[l].w1T = w1T[l]; pa.l[l].w2sT = w2sT[l]; pa.l[l].bias2 = bias2[l];
        pa.l[l].DIN = DIN[l]; pa.l[l].DOUT = DOUT[l];
    }
    dim3 pgrid(cdiv_l(64 * 128 + 96 * 64 + 96, B), 3);
    prep_all_kernel<<<pgrid, B, 0, stream>>>(pa, deg, cursor, (float*)d_out, partials);

    // ---- CSR histogram + scan ----
    deg_hist_kernel<<<cdiv_l(N_EDGES, B), B, 0, stream>>>(dst, deg, N_EDGES);
    int nblk = cdiv_l(N_NODES + 1, 1024);  // 98 blocks, all co-resident
    scan_fused_kernel<<<nblk, 1024, 0, stream>>>(deg, rowptr, partials, N_NODES, N_EDGES);

    // ---- merged CSR-fill (XCD-binned) + layer-0 pre-GEMM ----
    const int nfill  = cdiv_l(N_EDGES, B);        // 2344
    const int ngemm  = cdiv_l(N_NODES, 64);       // 1563
    const int ngrp_f = cdiv_l(nfill, 3);          // 782
    const int ngrp_g = cdiv_l(ngemm, 2);          // 782
    const int ngroups = (ngrp_f > ngrp_g) ? ngrp_f : ngrp_g;
    fill_pre_kernel<<<ngroups * 5, B, 0, stream>>>(
        src, dst, rowptr, cursor, eids, batch, gstart,
        x, w1T[0], yA, N_EDGES, N_NODES);

    const int ntiles = cdiv_l(N_NODES, 64);

    // ---- layer 0 (gather fused into MLP) ----
    fused_gather_mid_kernel<<<ntiles, 512, 0, stream>>>(
        yA, rowptr, eids, P[0][1], w2sT[0], bias2[0], w1T[1], yB, N_NODES);
    // ---- layer 1 ----
    fused_gather_mid_kernel<<<ntiles, 512, 0, stream>>>(
        yB, rowptr, eids, P[1][1], w2sT[1], bias2[1], w1T[2], yA, N_NODES);
    // ---- layer 2 (+ pool fused) ----
    fused_gather_final_kernel<<<ntiles, 512, 0, stream>>>(
        yA, rowptr, eids, P[2][1], w2sT[2], bias2[2], batch, gstart,
        (float*)d_out, N_NODES);
}